// Round 11
// baseline (196.517 us; speedup 1.0000x reference)
//
#include <hip/hip_runtime.h>
#include <hip/hip_bf16.h>

// ---------------------------------------------------------------------------
// MonotonicAlignmentSearch R11: R10 + XCD-aware conv block swizzle
// (flat = btg*64+og so same-o-tile blocks share an XCD's L2 -> weights
// fetched once per XCD instead of 8x). B=2, TT=128, TA=512, H=1024.
// ---------------------------------------------------------------------------

typedef __bf16 bf16_t;
typedef __bf16 bf16x8 __attribute__((ext_vector_type(8)));
typedef __bf16 bf16x4 __attribute__((ext_vector_type(4)));
typedef float  f32x4  __attribute__((ext_vector_type(4)));
typedef _Float16 f16_t;
typedef _Float16 f16x2 __attribute__((ext_vector_type(2)));
typedef _Float16 f16x4 __attribute__((ext_vector_type(4)));

#define EPSV 1e-5f

// ---- workspace offsets (bytes) — no overlays, ~26.2 MB << 256 MB ws -------
#define OFF_TEXTBF   0u          //  524288  bf16 text [256][1024]
#define OFF_AUDIOBF  524288u     // 2097152  bf16 audio [1024][1024]
#define OFF_W1TOP    2621440u    // 2097152  bf16 W1topT [1024][1024]
#define OFF_W1BOT    4718592u    // 2097152  bf16 W1botT [1024][1024]
#define OFF_WC1      6815744u    // 6291456  bf16 Wc1 [3][1024][1024]
#define OFF_WC2      13107200u   // 6291456  bf16 Wc2 [3][1024][1024]
#define OFF_TP       19398656u   //  524288  f16 tp [256][1024] (bias folded)
#define OFF_W2F      19922944u   //    2048  f16 w2 [1024]
#define OFF_APT      20447232u   // 2097152  f16 apT4 [256 hq][1024 ba][4]
#define OFF_XP0      22544384u   //  532480  bf16 xp0 [2][130][1024]
#define OFF_XP1      23076864u   //  532480  bf16 xp1 [2][130][1024]
#define OFF_Y2       23609344u   //  524288  bf16 y2 [256][1024] (pre-GN2)
#define OFF_STATS    24133632u   //      32  8 f32 GN stats
#define OFF_LP       24137728u   // 2097152  f32 lp [4 hc][256 bt][512 a]

// ---------------------------------------------------------------------------
// prep: [0,1280) cvt activations; [1280,3328) w1 transpose-cast;
// [3328,5376) conv-weight cvt; 5376: zero pads + stats + w2->f16.
// ---------------------------------------------------------------------------
__global__ __launch_bounds__(256) void prep_k(
    const float* __restrict__ text, const float* __restrict__ audio,
    const float* __restrict__ w1,
    const float* __restrict__ w1c, const float* __restrict__ w2c,
    const float* __restrict__ w2,
    bf16_t* __restrict__ text_bf, bf16_t* __restrict__ xp0,
    bf16_t* __restrict__ audio_bf,
    bf16_t* __restrict__ topT, bf16_t* __restrict__ botT,
    bf16_t* __restrict__ wc1, bf16_t* __restrict__ wc2,
    bf16_t* __restrict__ xp1, float* __restrict__ stats,
    f16_t* __restrict__ w2f)
{
    __shared__ float tile[32][33];
    const int bid = blockIdx.x;
    if (bid < 1280) {
        const int e = (bid * 256 + threadIdx.x) * 4;   // 1310720 total
        if (e < 262144) {
            float4 v = *(const float4*)&text[e];
            bf16x4 o; o[0] = (bf16_t)v.x; o[1] = (bf16_t)v.y; o[2] = (bf16_t)v.z; o[3] = (bf16_t)v.w;
            *(bf16x4*)&text_bf[e] = o;
            const int bt = e >> 10, h = e & 1023;
            const int b = bt >> 7, t = bt & 127;
            *(bf16x4*)&xp0[(size_t)(b * 130 + 1 + t) * 1024 + h] = o;
        } else {
            const int ea = e - 262144;
            float4 v = *(const float4*)&audio[ea];
            bf16x4 o; o[0] = (bf16_t)v.x; o[1] = (bf16_t)v.y; o[2] = (bf16_t)v.z; o[3] = (bf16_t)v.w;
            *(bf16x4*)&audio_bf[ea] = o;
        }
    } else if (bid < 3328) {
        const int b2 = bid - 1280;
        const int bx = b2 & 31, by = b2 >> 5;          // (32, 64)
        const int tx = threadIdx.x & 31, ty = threadIdx.x >> 5;
        #pragma unroll
        for (int j = 0; j < 4; ++j)
            tile[ty + j * 8][tx] = w1[(size_t)(by * 32 + ty + j * 8) * 1024 + bx * 32 + tx];
        __syncthreads();
        bf16_t* out = (by < 32) ? topT : botT;
        const int hbase = (by & 31) * 32;
        #pragma unroll
        for (int j = 0; j < 4; ++j) {
            const int d = bx * 32 + ty + j * 8;
            out[(size_t)d * 1024 + hbase + tx] = (bf16_t)tile[tx][ty + j * 8];
        }
    } else if (bid < 5376) {
        int b2 = bid - 3328;
        const float* w = (b2 < 1024) ? w1c : w2c;
        bf16_t* wc = (b2 < 1024) ? wc1 : wc2;
        b2 &= 1023;
        const int t = b2 * 256 + threadIdx.x;
        const int o = t >> 8, i4 = t & 255;
        const float* src = w + (size_t)o * 3072 + i4 * 12;
        float4 v0 = *(const float4*)&src[0];
        float4 v1 = *(const float4*)&src[4];
        float4 v2 = *(const float4*)&src[8];
        const float f[12] = {v0.x, v0.y, v0.z, v0.w, v1.x, v1.y, v1.z, v1.w, v2.x, v2.y, v2.z, v2.w};
        #pragma unroll
        for (int r = 0; r < 3; ++r) {
            bf16x4 o4;
            #pragma unroll
            for (int j = 0; j < 4; ++j) o4[j] = (bf16_t)f[j * 3 + r];
            *(bf16x4*)&wc[(size_t)r * 1048576 + (size_t)o * 1024 + i4 * 4] = o4;
        }
    } else {
        const int tid = threadIdx.x;
        const int rowmap[4] = {0, 129, 130, 259};
        const int f = tid * 16;
        const int r = f >> 10, w = f & 1023;
        bf16x8 z8 = (bf16x8)(bf16_t)0.0f;
        bf16_t* p0 = xp0 + (size_t)rowmap[r] * 1024 + w;
        bf16_t* p1 = xp1 + (size_t)rowmap[r] * 1024 + w;
        *(bf16x8*)p0 = z8; *(bf16x8*)(p0 + 8) = z8;
        *(bf16x8*)p1 = z8; *(bf16x8*)(p1 + 8) = z8;
        if (tid < 8) stats[tid] = 0.0f;
        float4 wv = *(const float4*)&w2[tid * 4];
        f16x4 wo; wo[0] = (f16_t)wv.x; wo[1] = (f16_t)wv.y; wo[2] = (f16_t)wv.z; wo[3] = (f16_t)wv.w;
        *(f16x4*)&w2f[tid * 4] = wo;
    }
}

// ---------------------------------------------------------------------------
// conv tile (16o x 32bt, 8 waves = i-chunks of 128, LDS split-k reduce,
// bias/relu + GN stats + bf16 transposed write). smem: 4608 floats.
// ---------------------------------------------------------------------------
__device__ __forceinline__ void conv_tile(
    const bf16_t* __restrict__ Wc, const bf16_t* __restrict__ xp,
    const float* __restrict__ bias, bf16_t* __restrict__ out,
    int rowsPerB, int rowOff, float* __restrict__ stats,
    int bx, int by, int tid, float* smem, float* sred, float* sredq)
{
    const int w = tid >> 6, l = tid & 63;
    const int bt0 = bx * 32, m0 = by * 16;
    const int i0 = w * 128;
    const int lm = l & 15, lk = (l >> 4) * 8;
    const int b = bt0 >> 7, tbase = bt0 & 127;
    f32x4 acc0 = (f32x4)(0.0f), acc1 = (f32x4)(0.0f);
    const bf16_t* aq = Wc + (size_t)(m0 + lm) * 1024 + i0 + lk;
    const bf16_t* bq = xp + (size_t)(b * 130 + tbase + lm) * 1024 + i0 + lk;
    #pragma unroll
    for (int r = 0; r < 3; ++r) {
        const bf16_t* ar = aq + (size_t)r * 1048576;
        const bf16_t* br = bq + (size_t)r * 1024;
        #pragma unroll
        for (int kk = 0; kk < 128; kk += 32) {
            bf16x8 af = *(const bf16x8*)(ar + kk);
            bf16x8 bf0 = *(const bf16x8*)(br + kk);
            bf16x8 bf1 = *(const bf16x8*)(br + 16384 + kk);
            acc0 = __builtin_amdgcn_mfma_f32_16x16x32_bf16(af, bf0, acc0, 0, 0, 0);
            acc1 = __builtin_amdgcn_mfma_f32_16x16x32_bf16(af, bf1, acc1, 0, 0, 0);
        }
    }
    {
        const int row = (l >> 4) * 4;
        #pragma unroll
        for (int r = 0; r < 4; ++r) {
            smem[w * 576 + (row + r) * 36 + lm] = acc0[r];
            smem[w * 576 + (row + r) * 36 + 16 + lm] = acc1[r];
        }
    }
    __syncthreads();
    const int m = tid >> 5, n = tid & 31;
    float v = 0.f;
    #pragma unroll
    for (int ww = 0; ww < 8; ++ww) v += smem[ww * 576 + m * 36 + n];
    v = fmaxf(v + bias[m0 + m], 0.f);
    float s = v, q = v * v;
    __syncthreads();
    smem[m * 36 + n] = v;
    #pragma unroll
    for (int off = 32; off > 0; off >>= 1) {
        s += __shfl_xor(s, off);
        q += __shfl_xor(q, off);
    }
    if (l == 0) { sred[w] = s; sredq[w] = q; }
    __syncthreads();
    if (tid == 0) {
        float ts = 0.f, tq = 0.f;
        #pragma unroll
        for (int ww = 0; ww < 8; ++ww) { ts += sred[ww]; tq += sredq[ww]; }
        atomicAdd(&stats[b * 2], ts);
        atomicAdd(&stats[b * 2 + 1], tq);
    }
    if (tid < 64) {
        const int row = tid >> 1, half = tid & 1;
        bf16x8 o8;
        #pragma unroll
        for (int j = 0; j < 8; ++j) o8[j] = (bf16_t)smem[(half * 8 + j) * 36 + row];
        const int t = tbase + row;
        *(bf16x8*)&out[(size_t)(b * rowsPerB + rowOff + t) * 1024 + m0 + half * 8] = o8;
    }
}

// ---------------------------------------------------------------------------
// tp/ap GEMM unit: 256 threads, 32x32 tile, 4-way k-split, LDS reduce.
// unit < 256: tp tile; else apT4 quad-packed tile. base: 4608 floats.
// ---------------------------------------------------------------------------
__device__ __forceinline__ void gemm_unit(
    int unit, int ut, float* base,
    const bf16_t* __restrict__ text_bf, const bf16_t* __restrict__ w1topT,
    const float* __restrict__ b1, f16_t* __restrict__ tp,
    const bf16_t* __restrict__ audio_bf, const bf16_t* __restrict__ w1botT,
    f16_t* __restrict__ apT4)
{
    const int is_tp = (unit < 256) ? 1 : 0;
    const int b2 = is_tp ? unit : unit - 256;
    const int n0 = (b2 & 31) * 32, m0 = (b2 >> 5) * 32;
    const int w = ut >> 6, l = ut & 63;
    const int lm = l & 15, lk = (l >> 4) * 8;
    const int k0 = w * 256;
    const bf16_t* A  = is_tp ? text_bf : audio_bf;
    const bf16_t* Bt = is_tp ? w1topT : w1botT;
    f32x4 acc[2][2];
    #pragma unroll
    for (int mt = 0; mt < 2; ++mt)
        #pragma unroll
        for (int nt = 0; nt < 2; ++nt) acc[mt][nt] = (f32x4)(0.0f);
    const bf16_t* Ap = A + (size_t)(m0 + lm) * 1024 + k0 + lk;
    const bf16_t* Bp = Bt + (size_t)(n0 + lm) * 1024 + k0 + lk;
    #pragma unroll
    for (int kk = 0; kk < 256; kk += 32) {
        bf16x8 af[2], bfr[2];
        #pragma unroll
        for (int i = 0; i < 2; ++i) af[i] = *(const bf16x8*)(Ap + (size_t)i * 16384 + kk);
        #pragma unroll
        for (int i = 0; i < 2; ++i) bfr[i] = *(const bf16x8*)(Bp + (size_t)i * 16384 + kk);
        #pragma unroll
        for (int mt = 0; mt < 2; ++mt)
            #pragma unroll
            for (int nt = 0; nt < 2; ++nt)
                acc[mt][nt] = __builtin_amdgcn_mfma_f32_16x16x32_bf16(af[mt], bfr[nt], acc[mt][nt], 0, 0, 0);
    }
    #pragma unroll
    for (int mt = 0; mt < 2; ++mt) {
        const int row = mt * 16 + (l >> 4) * 4;
        #pragma unroll
        for (int nt = 0; nt < 2; ++nt)
            #pragma unroll
            for (int r = 0; r < 4; ++r)
                base[w * 1152 + (row + r) * 36 + nt * 16 + lm] = acc[mt][nt][r];
    }
    __syncthreads();
    if (is_tp) {
        const int m = ut >> 3, n4 = (ut & 7) * 4;
        f16x4 v;
        #pragma unroll
        for (int j = 0; j < 4; ++j)
            v[j] = (f16_t)(base[m * 36 + n4 + j] + base[1152 + m * 36 + n4 + j]
                         + base[2304 + m * 36 + n4 + j] + base[3456 + m * 36 + n4 + j]
                         + b1[n0 + n4 + j]);
        *(f16x4*)&tp[(size_t)(m0 + m) * 1024 + n0 + n4] = v;
    } else {
        const int a = ut >> 3, q = ut & 7;
        const int b = m0 >> 9, a0 = m0 & 511;
        f16x4 v;
        #pragma unroll
        for (int c = 0; c < 4; ++c)
            v[c] = (f16_t)(base[a * 36 + q * 4 + c] + base[1152 + a * 36 + q * 4 + c]
                         + base[2304 + a * 36 + q * 4 + c] + base[3456 + a * 36 + q * 4 + c]);
        const size_t hq = (size_t)(n0 >> 2) + q;
        *(f16x4*)&apT4[(hq * 1024 + b * 512 + a0 + a) * 4] = v;
    }
}

// ---------------------------------------------------------------------------
// P2: blocks [0,512) conv1 tiles (XCD-swizzled: btg = bid>>6, og = bid&63 so
// same-og blocks land on one XCD); [512,1152) two gemm units each.
// ---------------------------------------------------------------------------
__global__ __launch_bounds__(512, 4) void p2_k(
    const bf16_t* __restrict__ wc1, const bf16_t* __restrict__ xp0,
    const float* __restrict__ d_b1, bf16_t* __restrict__ xp1,
    float* __restrict__ stats,
    const bf16_t* __restrict__ text_bf, const bf16_t* __restrict__ w1topT,
    const float* __restrict__ a_b1, f16_t* __restrict__ tp,
    const bf16_t* __restrict__ audio_bf, const bf16_t* __restrict__ w1botT,
    f16_t* __restrict__ apT4)
{
    __shared__ float smem[9216];
    __shared__ float sred[8], sredq[8];
    const int bid = blockIdx.x;
    const int tid = threadIdx.x;
    if (bid < 512) {
        // XCD swizzle: flat = btg*64 + og -> same og => same (bid mod 8) => same XCD
        conv_tile(wc1, xp0, d_b1, xp1, 130, 1, stats,
                  bid >> 6, bid & 63, tid, smem, sred, sredq);
    } else {
        const int unit = (bid - 512) * 2 + (tid >> 8);
        gemm_unit(unit, tid & 255, smem + (tid >> 8) * 4608,
                  text_bf, w1topT, a_b1, tp, audio_bf, w1botT, apT4);
    }
}

// ---------------------------------------------------------------------------
// P3: blocks [0,256) logits 4-t tiles; [256,384) GN1-apply chunks.
// ---------------------------------------------------------------------------
__device__ __forceinline__ float dot2_acc(f16x2 x, f16x2 w, float acc) {
#if __has_builtin(__builtin_amdgcn_fdot2)
    return __builtin_amdgcn_fdot2(x, w, acc, false);
#else
    return acc + (float)x[0] * (float)w[0] + (float)x[1] * (float)w[1];
#endif
}

__global__ __launch_bounds__(512) void p3_k(
    const f16_t* __restrict__ tp, const f16_t* __restrict__ apT4,
    const f16_t* __restrict__ w2f, float* __restrict__ lp,
    bf16_t* __restrict__ xp1, const float* __restrict__ stats,
    const float* __restrict__ g, const float* __restrict__ bet)
{
    const int bid = blockIdx.x;
    const int tid = threadIdx.x;
    if (bid < 256) {
        const int btp = bid & 63, hc = bid >> 6;
        const int bt0 = btp * 4;
        const int b = bt0 >> 7;
        const int a = tid;
        const f16_t* tpr = tp + (size_t)bt0 * 1024 + hc * 256;   // wave-uniform
        const f16_t* w2r = w2f + hc * 256;
        const f16_t* apc = apT4 + ((size_t)(hc * 64) * 1024 + b * 512 + a) * 4;
        float acc[4] = {0.f, 0.f, 0.f, 0.f};
        const f16x2 zero = (f16x2)(f16_t)0.0f;
        #pragma unroll 2
        for (int hq = 0; hq < 64; hq += 2) {                    // 8 h per iter
            f16x4 a0 = *(const f16x4*)(apc + (size_t)hq * 4096);
            f16x4 a1 = *(const f16x4*)(apc + (size_t)(hq + 1) * 4096);
            f16x4 w0 = *(const f16x4*)&w2r[hq * 4];
            f16x4 w1 = *(const f16x4*)&w2r[hq * 4 + 4];
            #pragma unroll
            for (int r = 0; r < 4; ++r) {
                f16x4 t0 = *(const f16x4*)&tpr[r * 1024 + hq * 4];
                f16x4 t1 = *(const f16x4*)&tpr[r * 1024 + hq * 4 + 4];
                f16x2 p;
                p = __builtin_elementwise_max((f16x2){t0[0] + a0[0], t0[1] + a0[1]}, zero);
                acc[r] = dot2_acc(p, (f16x2){w0[0], w0[1]}, acc[r]);
                p = __builtin_elementwise_max((f16x2){t0[2] + a0[2], t0[3] + a0[3]}, zero);
                acc[r] = dot2_acc(p, (f16x2){w0[2], w0[3]}, acc[r]);
                p = __builtin_elementwise_max((f16x2){t1[0] + a1[0], t1[1] + a1[1]}, zero);
                acc[r] = dot2_acc(p, (f16x2){w1[0], w1[1]}, acc[r]);
                p = __builtin_elementwise_max((f16x2){t1[2] + a1[2], t1[3] + a1[3]}, zero);
                acc[r] = dot2_acc(p, (f16x2){w1[2], w1[3]}, acc[r]);
            }
        }
        float* dst = lp + (size_t)(hc * 256 + bt0) * 512 + a;
        #pragma unroll
        for (int r = 0; r < 4; ++r) dst[(size_t)r * 512] = acc[r];
    } else {
        // GN1 apply in-place on padded xp1
        const int idx4 = (bid - 256) * 512 + tid;   // 65536 total
        const int e = idx4 * 4;
        const int bt = e >> 10, o = e & 1023;
        const int b = bt >> 7, t = bt & 127;
        bf16_t* p = xp1 + (size_t)(b * 130 + 1 + t) * 1024 + o;
        const float cnt = 131072.f;
        const float mu = stats[b * 2] / cnt;
        const float var = stats[b * 2 + 1] / cnt - mu * mu;
        const float rs = rsqrtf(var + EPSV);
        bf16x4 v = *(bf16x4*)p;
        float4 gv = *(const float4*)&g[o];
        float4 bv = *(const float4*)&bet[o];
        bf16x4 ov;
        ov[0] = (bf16_t)(((float)v[0] - mu) * rs * gv.x + bv.x);
        ov[1] = (bf16_t)(((float)v[1] - mu) * rs * gv.y + bv.y);
        ov[2] = (bf16_t)(((float)v[2] - mu) * rs * gv.z + bv.z);
        ov[3] = (bf16_t)(((float)v[3] - mu) * rs * gv.w + bv.w);
        *(bf16x4*)p = ov;
    }
}

// conv2 standalone (512 blocks, XCD-swizzled like conv1)
__global__ __launch_bounds__(512, 4) void conv2_k(
    const bf16_t* __restrict__ wc2, const bf16_t* __restrict__ xp1,
    const float* __restrict__ d_b2, bf16_t* __restrict__ y2,
    float* __restrict__ stats2)
{
    __shared__ float smem[4608];
    __shared__ float sred[8], sredq[8];
    conv_tile(wc2, xp1, d_b2, y2, 128, 0, stats2,
              blockIdx.x >> 6, blockIdx.x & 63, threadIdx.x, smem, sred, sredq);
}

// ---------------------------------------------------------------------------
// combine: blocks [0,256): sum lp chunks + bias + monotonic, softmax -> out.
//          blocks [256,288): conv3 + GN2-fold + softplus -> durations.
// ---------------------------------------------------------------------------
__global__ __launch_bounds__(512) void combine_k(
    const float* __restrict__ lp, const float* __restrict__ b2,
    const bf16_t* __restrict__ y2, const float* __restrict__ stats2,
    const float* __restrict__ g, const float* __restrict__ bet,
    const float* __restrict__ w3, const float* __restrict__ b3,
    float* __restrict__ out)
{
    __shared__ float redm[8], redsum[8];
    const int bid = blockIdx.x;
    const int tid = threadIdx.x;
    if (bid < 256) {
        const int bt = bid, t = bt & 127;
        const int a = tid;
        const int lane = a & 63, wid = a >> 6;
        const size_t base = (size_t)bt * 512 + a;
        float v = lp[base] + lp[131072 + base] + lp[262144 + base] + lp[393216 + base];
        v += b2[0] - 0.1f * fabsf((float)a - 4.0f * (float)t);
        float m = v;
        #pragma unroll
        for (int off = 32; off > 0; off >>= 1) m = fmaxf(m, __shfl_xor(m, off));
        if (lane == 0) redm[wid] = m;
        __syncthreads();
        float M = redm[0];
        #pragma unroll
        for (int i = 1; i < 8; ++i) M = fmaxf(M, redm[i]);
        const float e = expf(v - M);
        float s = e;
        #pragma unroll
        for (int off = 32; off > 0; off >>= 1) s += __shfl_xor(s, off);
        if (lane == 0) redsum[wid] = s;
        __syncthreads();
        float S = redsum[0];
        #pragma unroll
        for (int i = 1; i < 8; ++i) S += redsum[i];
        out[(size_t)bt * 512 + a] = e * (1.0f / S);
    } else {
        const int lane = tid & 63, w = tid >> 6;
        const int bt = (bid - 256) * 8 + w;
        const int b = bt >> 7;
        const float cnt = 131072.f;
        const float mu = stats2[b * 2] / cnt;
        const float var = stats2[b * 2 + 1] / cnt - mu * mu;
        const float rs = rsqrtf(var + EPSV);
        const bf16_t* row = y2 + (size_t)bt * 1024 + lane * 16;
        float s1 = 0.f, s2 = 0.f, s3 = 0.f;
        #pragma unroll
        for (int c = 0; c < 2; ++c) {
            bf16x8 yv = *(const bf16x8*)(row + c * 8);
            #pragma unroll
            for (int j = 0; j < 8; ++j) {
                const int i = lane * 16 + c * 8 + j;
                const float gw = g[i] * w3[i];
                s1 += gw * (float)yv[j];
                s2 += gw;
                s3 += bet[i] * w3[i];
            }
        }
        #pragma unroll
        for (int off = 32; off > 0; off >>= 1) {
            s1 += __shfl_xor(s1, off);
            s2 += __shfl_xor(s2, off);
            s3 += __shfl_xor(s3, off);
        }
        if (lane == 0) {
            const float t = rs * (s1 - mu * s2) + s3 + b3[0];
            out[131072 + bt] = fmaxf(t, 0.f) + log1pf(expf(-fabsf(t)));
        }
    }
}

extern "C" void kernel_launch(void* const* d_in, const int* in_sizes, int n_in,
                              void* d_out, int out_size, void* d_ws, size_t ws_size,
                              hipStream_t stream) {
    const float* text   = (const float*)d_in[0];
    const float* audio  = (const float*)d_in[1];
    const float* a_w1   = (const float*)d_in[2];
    const float* a_b1   = (const float*)d_in[3];
    const float* a_w2   = (const float*)d_in[4];
    const float* a_b2   = (const float*)d_in[5];
    const float* d_w1   = (const float*)d_in[6];
    const float* d_b1   = (const float*)d_in[7];
    const float* gn1_g  = (const float*)d_in[8];
    const float* gn1_b  = (const float*)d_in[9];
    const float* d_w2   = (const float*)d_in[10];
    const float* d_b2   = (const float*)d_in[11];
    const float* gn2_g  = (const float*)d_in[12];
    const float* gn2_b  = (const float*)d_in[13];
    const float* d_w3   = (const float*)d_in[14];
    const float* d_b3   = (const float*)d_in[15];

    char* ws = (char*)d_ws;
    float* outf = (float*)d_out;

    bf16_t* text_bf  = (bf16_t*)(ws + OFF_TEXTBF);
    bf16_t* audio_bf = (bf16_t*)(ws + OFF_AUDIOBF);
    bf16_t* w1topT   = (bf16_t*)(ws + OFF_W1TOP);
    bf16_t* w1botT   = (bf16_t*)(ws + OFF_W1BOT);
    bf16_t* wc1      = (bf16_t*)(ws + OFF_WC1);
    bf16_t* wc2      = (bf16_t*)(ws + OFF_WC2);
    f16_t*  tp       = (f16_t*) (ws + OFF_TP);
    f16_t*  w2f      = (f16_t*) (ws + OFF_W2F);
    f16_t*  apT4     = (f16_t*) (ws + OFF_APT);
    bf16_t* xp0      = (bf16_t*)(ws + OFF_XP0);
    bf16_t* xp1      = (bf16_t*)(ws + OFF_XP1);
    bf16_t* y2       = (bf16_t*)(ws + OFF_Y2);
    float*  stats    = (float*) (ws + OFF_STATS);
    float*  lp       = (float*) (ws + OFF_LP);

    // 1: prep (cvt activations, w1 transpose, conv weights, pads/stats, w2f)
    prep_k<<<dim3(5377), 256, 0, stream>>>(text, audio, a_w1, d_w1, d_w2, a_w2,
                                           text_bf, xp0, audio_bf, w1topT, w1botT,
                                           wc1, wc2, xp1, stats, w2f);
    // 2: conv1 (blocks 0..511, XCD-swizzled) ∥ tp/ap GEMM (512..1151)
    p2_k<<<dim3(1152), 512, 0, stream>>>(wc1, xp0, d_b1, xp1, stats,
                                         text_bf, w1topT, a_b1, tp,
                                         audio_bf, w1botT, apT4);
    // 3: logits partials (blocks 0..255, 4 t/block) ∥ GN1 apply (256..383)
    p3_k<<<dim3(384), 512, 0, stream>>>(tp, apT4, w2f, lp,
                                        xp1, stats, gn1_g, gn1_b);
    // 4: conv2 -> y2 (pre-GN2, XCD-swizzled)
    conv2_k<<<dim3(512), 512, 0, stream>>>(wc2, xp1, d_b2, y2, stats + 4);
    // 5: combine+softmax -> alignment; conv3+GN2fold+softplus -> durations
    combine_k<<<dim3(288), 512, 0, stream>>>(lp, a_b2, y2, stats + 4,
                                             gn2_g, gn2_b, d_w3, d_b3, outf);
}

// Round 12
// 183.418 us; speedup vs baseline: 1.0714x; 1.0714x over previous
//
#include <hip/hip_runtime.h>
#include <hip/hip_bf16.h>

// ---------------------------------------------------------------------------
// MonotonicAlignmentSearch R12: R11 + atomic-free GN stats (two-level
// reduction: per-block partials -> consumer-side reduce). The ~45 µs conv
// dispatches were serialized cross-XCD atomicAdd drains on 4 addresses.
// B=2, TT=128, TA=512, H=1024.
// ---------------------------------------------------------------------------

typedef __bf16 bf16_t;
typedef __bf16 bf16x8 __attribute__((ext_vector_type(8)));
typedef __bf16 bf16x4 __attribute__((ext_vector_type(4)));
typedef float  f32x4  __attribute__((ext_vector_type(4)));
typedef _Float16 f16_t;
typedef _Float16 f16x2 __attribute__((ext_vector_type(2)));
typedef _Float16 f16x4 __attribute__((ext_vector_type(4)));

#define EPSV 1e-5f

// ---- workspace offsets (bytes) — no overlays, ~26.2 MB << 256 MB ws -------
#define OFF_TEXTBF   0u          //  524288  bf16 text [256][1024]
#define OFF_AUDIOBF  524288u     // 2097152  bf16 audio [1024][1024]
#define OFF_W1TOP    2621440u    // 2097152  bf16 W1topT [1024][1024]
#define OFF_W1BOT    4718592u    // 2097152  bf16 W1botT [1024][1024]
#define OFF_WC1      6815744u    // 6291456  bf16 Wc1 [3][1024][1024]
#define OFF_WC2      13107200u   // 6291456  bf16 Wc2 [3][1024][1024]
#define OFF_TP       19398656u   //  524288  f16 tp [256][1024] (bias folded)
#define OFF_W2F      19922944u   //    2048  f16 w2 [1024]
#define OFF_APT      20447232u   // 2097152  f16 apT4 [256 hq][1024 ba][4]
#define OFF_XP0      22544384u   //  532480  bf16 xp0 [2][130][1024]
#define OFF_XP1      23076864u   //  532480  bf16 xp1 [2][130][1024]
#define OFF_Y2       23609344u   //  524288  bf16 y2 [256][1024] (pre-GN2)
#define OFF_BST1     24133632u   //    4096  f32 bstat1 [512][2] (conv1 partials)
#define OFF_BST2     24137728u   //    4096  f32 bstat2 [512][2] (conv2 partials)
#define OFF_LP       24141824u   // 2097152  f32 lp [4 hc][256 bt][512 a]

// ---------------------------------------------------------------------------
// prep: [0,1280) cvt activations; [1280,3328) w1 transpose-cast;
// [3328,5376) conv-weight cvt; 5376: zero pads + w2->f16.
// ---------------------------------------------------------------------------
__global__ __launch_bounds__(256) void prep_k(
    const float* __restrict__ text, const float* __restrict__ audio,
    const float* __restrict__ w1,
    const float* __restrict__ w1c, const float* __restrict__ w2c,
    const float* __restrict__ w2,
    bf16_t* __restrict__ text_bf, bf16_t* __restrict__ xp0,
    bf16_t* __restrict__ audio_bf,
    bf16_t* __restrict__ topT, bf16_t* __restrict__ botT,
    bf16_t* __restrict__ wc1, bf16_t* __restrict__ wc2,
    bf16_t* __restrict__ xp1, f16_t* __restrict__ w2f)
{
    __shared__ float tile[32][33];
    const int bid = blockIdx.x;
    if (bid < 1280) {
        const int e = (bid * 256 + threadIdx.x) * 4;   // 1310720 total
        if (e < 262144) {
            float4 v = *(const float4*)&text[e];
            bf16x4 o; o[0] = (bf16_t)v.x; o[1] = (bf16_t)v.y; o[2] = (bf16_t)v.z; o[3] = (bf16_t)v.w;
            *(bf16x4*)&text_bf[e] = o;
            const int bt = e >> 10, h = e & 1023;
            const int b = bt >> 7, t = bt & 127;
            *(bf16x4*)&xp0[(size_t)(b * 130 + 1 + t) * 1024 + h] = o;
        } else {
            const int ea = e - 262144;
            float4 v = *(const float4*)&audio[ea];
            bf16x4 o; o[0] = (bf16_t)v.x; o[1] = (bf16_t)v.y; o[2] = (bf16_t)v.z; o[3] = (bf16_t)v.w;
            *(bf16x4*)&audio_bf[ea] = o;
        }
    } else if (bid < 3328) {
        const int b2 = bid - 1280;
        const int bx = b2 & 31, by = b2 >> 5;          // (32, 64)
        const int tx = threadIdx.x & 31, ty = threadIdx.x >> 5;
        #pragma unroll
        for (int j = 0; j < 4; ++j)
            tile[ty + j * 8][tx] = w1[(size_t)(by * 32 + ty + j * 8) * 1024 + bx * 32 + tx];
        __syncthreads();
        bf16_t* out = (by < 32) ? topT : botT;
        const int hbase = (by & 31) * 32;
        #pragma unroll
        for (int j = 0; j < 4; ++j) {
            const int d = bx * 32 + ty + j * 8;
            out[(size_t)d * 1024 + hbase + tx] = (bf16_t)tile[tx][ty + j * 8];
        }
    } else if (bid < 5376) {
        int b2 = bid - 3328;
        const float* w = (b2 < 1024) ? w1c : w2c;
        bf16_t* wc = (b2 < 1024) ? wc1 : wc2;
        b2 &= 1023;
        const int t = b2 * 256 + threadIdx.x;
        const int o = t >> 8, i4 = t & 255;
        const float* src = w + (size_t)o * 3072 + i4 * 12;
        float4 v0 = *(const float4*)&src[0];
        float4 v1 = *(const float4*)&src[4];
        float4 v2 = *(const float4*)&src[8];
        const float f[12] = {v0.x, v0.y, v0.z, v0.w, v1.x, v1.y, v1.z, v1.w, v2.x, v2.y, v2.z, v2.w};
        #pragma unroll
        for (int r = 0; r < 3; ++r) {
            bf16x4 o4;
            #pragma unroll
            for (int j = 0; j < 4; ++j) o4[j] = (bf16_t)f[j * 3 + r];
            *(bf16x4*)&wc[(size_t)r * 1048576 + (size_t)o * 1024 + i4 * 4] = o4;
        }
    } else {
        const int tid = threadIdx.x;
        const int rowmap[4] = {0, 129, 130, 259};
        const int f = tid * 16;
        const int r = f >> 10, w = f & 1023;
        bf16x8 z8 = (bf16x8)(bf16_t)0.0f;
        bf16_t* p0 = xp0 + (size_t)rowmap[r] * 1024 + w;
        bf16_t* p1 = xp1 + (size_t)rowmap[r] * 1024 + w;
        *(bf16x8*)p0 = z8; *(bf16x8*)(p0 + 8) = z8;
        *(bf16x8*)p1 = z8; *(bf16x8*)(p1 + 8) = z8;
        float4 wv = *(const float4*)&w2[tid * 4];
        f16x4 wo; wo[0] = (f16_t)wv.x; wo[1] = (f16_t)wv.y; wo[2] = (f16_t)wv.z; wo[3] = (f16_t)wv.w;
        *(f16x4*)&w2f[tid * 4] = wo;
    }
}

// ---------------------------------------------------------------------------
// conv tile (16o x 32bt, 8 waves = i-chunks of 128, LDS split-k reduce,
// bias/relu + per-block GN partial store + bf16 transposed write).
// NO atomics: partials -> bstat[statIdx].
// ---------------------------------------------------------------------------
__device__ __forceinline__ void conv_tile(
    const bf16_t* __restrict__ Wc, const bf16_t* __restrict__ xp,
    const float* __restrict__ bias, bf16_t* __restrict__ out,
    int rowsPerB, int rowOff, float* __restrict__ bstat, int statIdx,
    int bx, int by, int tid, float* smem, float* sred, float* sredq)
{
    const int w = tid >> 6, l = tid & 63;
    const int bt0 = bx * 32, m0 = by * 16;
    const int i0 = w * 128;
    const int lm = l & 15, lk = (l >> 4) * 8;
    const int b = bt0 >> 7, tbase = bt0 & 127;
    f32x4 acc0 = (f32x4)(0.0f), acc1 = (f32x4)(0.0f);
    const bf16_t* aq = Wc + (size_t)(m0 + lm) * 1024 + i0 + lk;
    const bf16_t* bq = xp + (size_t)(b * 130 + tbase + lm) * 1024 + i0 + lk;
    #pragma unroll
    for (int r = 0; r < 3; ++r) {
        const bf16_t* ar = aq + (size_t)r * 1048576;
        const bf16_t* br = bq + (size_t)r * 1024;
        #pragma unroll
        for (int kk = 0; kk < 128; kk += 32) {
            bf16x8 af = *(const bf16x8*)(ar + kk);
            bf16x8 bf0 = *(const bf16x8*)(br + kk);
            bf16x8 bf1 = *(const bf16x8*)(br + 16384 + kk);
            acc0 = __builtin_amdgcn_mfma_f32_16x16x32_bf16(af, bf0, acc0, 0, 0, 0);
            acc1 = __builtin_amdgcn_mfma_f32_16x16x32_bf16(af, bf1, acc1, 0, 0, 0);
        }
    }
    {
        const int row = (l >> 4) * 4;
        #pragma unroll
        for (int r = 0; r < 4; ++r) {
            smem[w * 576 + (row + r) * 36 + lm] = acc0[r];
            smem[w * 576 + (row + r) * 36 + 16 + lm] = acc1[r];
        }
    }
    __syncthreads();
    const int m = tid >> 5, n = tid & 31;
    float v = 0.f;
    #pragma unroll
    for (int ww = 0; ww < 8; ++ww) v += smem[ww * 576 + m * 36 + n];
    v = fmaxf(v + bias[m0 + m], 0.f);
    float s = v, q = v * v;
    __syncthreads();
    smem[m * 36 + n] = v;
    #pragma unroll
    for (int off = 32; off > 0; off >>= 1) {
        s += __shfl_xor(s, off);
        q += __shfl_xor(q, off);
    }
    if (l == 0) { sred[w] = s; sredq[w] = q; }
    __syncthreads();
    if (tid == 0) {
        float ts = 0.f, tq = 0.f;
        #pragma unroll
        for (int ww = 0; ww < 8; ++ww) { ts += sred[ww]; tq += sredq[ww]; }
        bstat[statIdx * 2] = ts;          // plain store — no atomics
        bstat[statIdx * 2 + 1] = tq;
    }
    if (tid < 64) {
        const int row = tid >> 1, half = tid & 1;
        bf16x8 o8;
        #pragma unroll
        for (int j = 0; j < 8; ++j) o8[j] = (bf16_t)smem[(half * 8 + j) * 36 + row];
        const int t = tbase + row;
        *(bf16x8*)&out[(size_t)(b * rowsPerB + rowOff + t) * 1024 + m0 + half * 8] = o8;
    }
}

// reduce 256 (s,q) pairs for batch b from bstat (512 blocks, swizzled so
// bids [0,256) are b=0, [256,512) are b=1). 512 threads; result broadcast.
__device__ __forceinline__ void reduce_bstat(
    const float* __restrict__ bstat, int b, int tid,
    float* sr, float* sq, float& mu, float& rsig)
{
    const int lane = tid & 63, wid = tid >> 6;
    float s = 0.f, q = 0.f;
    if (tid < 256) {
        float2 v = ((const float2*)bstat)[b * 256 + tid];
        s = v.x; q = v.y;
    }
    #pragma unroll
    for (int off = 32; off > 0; off >>= 1) {
        s += __shfl_xor(s, off);
        q += __shfl_xor(q, off);
    }
    if (lane == 0) { sr[wid] = s; sq[wid] = q; }
    __syncthreads();
    float ts = 0.f, tq = 0.f;
    #pragma unroll
    for (int i = 0; i < 8; ++i) { ts += sr[i]; tq += sq[i]; }
    const float cnt = 131072.f;
    mu = ts / cnt;
    const float var = tq / cnt - mu * mu;
    rsig = rsqrtf(var + EPSV);
}

// ---------------------------------------------------------------------------
// tp/ap GEMM unit: 256 threads, 32x32 tile, 4-way k-split, LDS reduce.
// ---------------------------------------------------------------------------
__device__ __forceinline__ void gemm_unit(
    int unit, int ut, float* base,
    const bf16_t* __restrict__ text_bf, const bf16_t* __restrict__ w1topT,
    const float* __restrict__ b1, f16_t* __restrict__ tp,
    const bf16_t* __restrict__ audio_bf, const bf16_t* __restrict__ w1botT,
    f16_t* __restrict__ apT4)
{
    const int is_tp = (unit < 256) ? 1 : 0;
    const int b2 = is_tp ? unit : unit - 256;
    const int n0 = (b2 & 31) * 32, m0 = (b2 >> 5) * 32;
    const int w = ut >> 6, l = ut & 63;
    const int lm = l & 15, lk = (l >> 4) * 8;
    const int k0 = w * 256;
    const bf16_t* A  = is_tp ? text_bf : audio_bf;
    const bf16_t* Bt = is_tp ? w1topT : w1botT;
    f32x4 acc[2][2];
    #pragma unroll
    for (int mt = 0; mt < 2; ++mt)
        #pragma unroll
        for (int nt = 0; nt < 2; ++nt) acc[mt][nt] = (f32x4)(0.0f);
    const bf16_t* Ap = A + (size_t)(m0 + lm) * 1024 + k0 + lk;
    const bf16_t* Bp = Bt + (size_t)(n0 + lm) * 1024 + k0 + lk;
    #pragma unroll
    for (int kk = 0; kk < 256; kk += 32) {
        bf16x8 af[2], bfr[2];
        #pragma unroll
        for (int i = 0; i < 2; ++i) af[i] = *(const bf16x8*)(Ap + (size_t)i * 16384 + kk);
        #pragma unroll
        for (int i = 0; i < 2; ++i) bfr[i] = *(const bf16x8*)(Bp + (size_t)i * 16384 + kk);
        #pragma unroll
        for (int mt = 0; mt < 2; ++mt)
            #pragma unroll
            for (int nt = 0; nt < 2; ++nt)
                acc[mt][nt] = __builtin_amdgcn_mfma_f32_16x16x32_bf16(af[mt], bfr[nt], acc[mt][nt], 0, 0, 0);
    }
    #pragma unroll
    for (int mt = 0; mt < 2; ++mt) {
        const int row = mt * 16 + (l >> 4) * 4;
        #pragma unroll
        for (int nt = 0; nt < 2; ++nt)
            #pragma unroll
            for (int r = 0; r < 4; ++r)
                base[w * 1152 + (row + r) * 36 + nt * 16 + lm] = acc[mt][nt][r];
    }
    __syncthreads();
    if (is_tp) {
        const int m = ut >> 3, n4 = (ut & 7) * 4;
        f16x4 v;
        #pragma unroll
        for (int j = 0; j < 4; ++j)
            v[j] = (f16_t)(base[m * 36 + n4 + j] + base[1152 + m * 36 + n4 + j]
                         + base[2304 + m * 36 + n4 + j] + base[3456 + m * 36 + n4 + j]
                         + b1[n0 + n4 + j]);
        *(f16x4*)&tp[(size_t)(m0 + m) * 1024 + n0 + n4] = v;
    } else {
        const int a = ut >> 3, q = ut & 7;
        const int b = m0 >> 9, a0 = m0 & 511;
        f16x4 v;
        #pragma unroll
        for (int c = 0; c < 4; ++c)
            v[c] = (f16_t)(base[a * 36 + q * 4 + c] + base[1152 + a * 36 + q * 4 + c]
                         + base[2304 + a * 36 + q * 4 + c] + base[3456 + a * 36 + q * 4 + c]);
        const size_t hq = (size_t)(n0 >> 2) + q;
        *(f16x4*)&apT4[(hq * 1024 + b * 512 + a0 + a) * 4] = v;
    }
}

// ---------------------------------------------------------------------------
// P2: blocks [0,512) conv1 tiles (XCD-swizzled); [512,1152) two gemm units.
// ---------------------------------------------------------------------------
__global__ __launch_bounds__(512, 4) void p2_k(
    const bf16_t* __restrict__ wc1, const bf16_t* __restrict__ xp0,
    const float* __restrict__ d_b1, bf16_t* __restrict__ xp1,
    float* __restrict__ bstat1,
    const bf16_t* __restrict__ text_bf, const bf16_t* __restrict__ w1topT,
    const float* __restrict__ a_b1, f16_t* __restrict__ tp,
    const bf16_t* __restrict__ audio_bf, const bf16_t* __restrict__ w1botT,
    f16_t* __restrict__ apT4)
{
    __shared__ float smem[9216];
    __shared__ float sred[8], sredq[8];
    const int bid = blockIdx.x;
    const int tid = threadIdx.x;
    if (bid < 512) {
        conv_tile(wc1, xp0, d_b1, xp1, 130, 1, bstat1, bid,
                  bid >> 6, bid & 63, tid, smem, sred, sredq);
    } else {
        const int unit = (bid - 512) * 2 + (tid >> 8);
        gemm_unit(unit, tid & 255, smem + (tid >> 8) * 4608,
                  text_bf, w1topT, a_b1, tp, audio_bf, w1botT, apT4);
    }
}

// ---------------------------------------------------------------------------
// P3: blocks [0,256) logits 4-t tiles; [256,384) GN1 reduce+apply chunks.
// ---------------------------------------------------------------------------
__device__ __forceinline__ float dot2_acc(f16x2 x, f16x2 w, float acc) {
#if __has_builtin(__builtin_amdgcn_fdot2)
    return __builtin_amdgcn_fdot2(x, w, acc, false);
#else
    return acc + (float)x[0] * (float)w[0] + (float)x[1] * (float)w[1];
#endif
}

__global__ __launch_bounds__(512) void p3_k(
    const f16_t* __restrict__ tp, const f16_t* __restrict__ apT4,
    const f16_t* __restrict__ w2f, float* __restrict__ lp,
    bf16_t* __restrict__ xp1, const float* __restrict__ bstat1,
    const float* __restrict__ g, const float* __restrict__ bet)
{
    __shared__ float sr[8], sq[8];
    const int bid = blockIdx.x;
    const int tid = threadIdx.x;
    if (bid < 256) {
        const int btp = bid & 63, hc = bid >> 6;
        const int bt0 = btp * 4;
        const int b = bt0 >> 7;
        const int a = tid;
        const f16_t* tpr = tp + (size_t)bt0 * 1024 + hc * 256;   // wave-uniform
        const f16_t* w2r = w2f + hc * 256;
        const f16_t* apc = apT4 + ((size_t)(hc * 64) * 1024 + b * 512 + a) * 4;
        float acc[4] = {0.f, 0.f, 0.f, 0.f};
        const f16x2 zero = (f16x2)(f16_t)0.0f;
        #pragma unroll 2
        for (int hq = 0; hq < 64; hq += 2) {                    // 8 h per iter
            f16x4 a0 = *(const f16x4*)(apc + (size_t)hq * 4096);
            f16x4 a1 = *(const f16x4*)(apc + (size_t)(hq + 1) * 4096);
            f16x4 w0 = *(const f16x4*)&w2r[hq * 4];
            f16x4 w1 = *(const f16x4*)&w2r[hq * 4 + 4];
            #pragma unroll
            for (int r = 0; r < 4; ++r) {
                f16x4 t0 = *(const f16x4*)&tpr[r * 1024 + hq * 4];
                f16x4 t1 = *(const f16x4*)&tpr[r * 1024 + hq * 4 + 4];
                f16x2 p;
                p = __builtin_elementwise_max((f16x2){t0[0] + a0[0], t0[1] + a0[1]}, zero);
                acc[r] = dot2_acc(p, (f16x2){w0[0], w0[1]}, acc[r]);
                p = __builtin_elementwise_max((f16x2){t0[2] + a0[2], t0[3] + a0[3]}, zero);
                acc[r] = dot2_acc(p, (f16x2){w0[2], w0[3]}, acc[r]);
                p = __builtin_elementwise_max((f16x2){t1[0] + a1[0], t1[1] + a1[1]}, zero);
                acc[r] = dot2_acc(p, (f16x2){w1[0], w1[1]}, acc[r]);
                p = __builtin_elementwise_max((f16x2){t1[2] + a1[2], t1[3] + a1[3]}, zero);
                acc[r] = dot2_acc(p, (f16x2){w1[2], w1[3]}, acc[r]);
            }
        }
        float* dst = lp + (size_t)(hc * 256 + bt0) * 512 + a;
        #pragma unroll
        for (int r = 0; r < 4; ++r) dst[(size_t)r * 512] = acc[r];
    } else {
        // GN1: reduce conv1 partials for this block's batch, then apply.
        const int gb = bid - 256;              // 0..127, covers bt [gb*2, gb*2+2)
        const int b = (gb * 2) >> 7;
        float mu, rsig;
        reduce_bstat(bstat1, b, tid, sr, sq, mu, rsig);
        const int idx4 = gb * 512 + tid;       // 65536 total
        const int e = idx4 * 4;
        const int bt = e >> 10, o = e & 1023;
        const int t = bt & 127;
        bf16_t* p = xp1 + (size_t)(b * 130 + 1 + t) * 1024 + o;
        bf16x4 v = *(bf16x4*)p;
        float4 gv = *(const float4*)&g[o];
        float4 bv = *(const float4*)&bet[o];
        bf16x4 ov;
        ov[0] = (bf16_t)(((float)v[0] - mu) * rsig * gv.x + bv.x);
        ov[1] = (bf16_t)(((float)v[1] - mu) * rsig * gv.y + bv.y);
        ov[2] = (bf16_t)(((float)v[2] - mu) * rsig * gv.z + bv.z);
        ov[3] = (bf16_t)(((float)v[3] - mu) * rsig * gv.w + bv.w);
        *(bf16x4*)p = ov;
    }
}

// conv2 standalone (512 blocks, XCD-swizzled, atomic-free)
__global__ __launch_bounds__(512, 4) void conv2_k(
    const bf16_t* __restrict__ wc2, const bf16_t* __restrict__ xp1,
    const float* __restrict__ d_b2, bf16_t* __restrict__ y2,
    float* __restrict__ bstat2)
{
    __shared__ float smem[4608];
    __shared__ float sred[8], sredq[8];
    conv_tile(wc2, xp1, d_b2, y2, 128, 0, bstat2, blockIdx.x,
              blockIdx.x >> 6, blockIdx.x & 63, threadIdx.x, smem, sred, sredq);
}

// ---------------------------------------------------------------------------
// combine: blocks [0,256): sum lp chunks + bias + monotonic, softmax -> out.
//          blocks [256,288): conv3 + GN2 (reduced from bstat2) + softplus.
// ---------------------------------------------------------------------------
__global__ __launch_bounds__(512) void combine_k(
    const float* __restrict__ lp, const float* __restrict__ b2,
    const bf16_t* __restrict__ y2, const float* __restrict__ bstat2,
    const float* __restrict__ g, const float* __restrict__ bet,
    const float* __restrict__ w3, const float* __restrict__ b3,
    float* __restrict__ out)
{
    __shared__ float redm[8], redsum[8];
    const int bid = blockIdx.x;
    const int tid = threadIdx.x;
    if (bid < 256) {
        const int bt = bid, t = bt & 127;
        const int a = tid;
        const int lane = a & 63, wid = a >> 6;
        const size_t base = (size_t)bt * 512 + a;
        float v = lp[base] + lp[131072 + base] + lp[262144 + base] + lp[393216 + base];
        v += b2[0] - 0.1f * fabsf((float)a - 4.0f * (float)t);
        float m = v;
        #pragma unroll
        for (int off = 32; off > 0; off >>= 1) m = fmaxf(m, __shfl_xor(m, off));
        if (lane == 0) redm[wid] = m;
        __syncthreads();
        float M = redm[0];
        #pragma unroll
        for (int i = 1; i < 8; ++i) M = fmaxf(M, redm[i]);
        const float e = expf(v - M);
        float s = e;
        #pragma unroll
        for (int off = 32; off > 0; off >>= 1) s += __shfl_xor(s, off);
        if (lane == 0) redsum[wid] = s;
        __syncthreads();
        float S = redsum[0];
        #pragma unroll
        for (int i = 1; i < 8; ++i) S += redsum[i];
        out[(size_t)bt * 512 + a] = e * (1.0f / S);
    } else {
        // conv3 + GN2-fold + softplus; mu/var reduced from conv2 partials.
        const int cb = bid - 256;              // 0..31, bt [cb*8, cb*8+8)
        const int b = (cb * 8) >> 7;
        float mu, rsig;
        reduce_bstat(bstat2, b, tid, redm, redsum, mu, rsig);
        const int lane = tid & 63, w = tid >> 6;
        const int bt = cb * 8 + w;
        const bf16_t* row = y2 + (size_t)bt * 1024 + lane * 16;
        float s1 = 0.f, s2 = 0.f, s3 = 0.f;
        #pragma unroll
        for (int c = 0; c < 2; ++c) {
            bf16x8 yv = *(const bf16x8*)(row + c * 8);
            #pragma unroll
            for (int j = 0; j < 8; ++j) {
                const int i = lane * 16 + c * 8 + j;
                const float gw = g[i] * w3[i];
                s1 += gw * (float)yv[j];
                s2 += gw;
                s3 += bet[i] * w3[i];
            }
        }
        #pragma unroll
        for (int off = 32; off > 0; off >>= 1) {
            s1 += __shfl_xor(s1, off);
            s2 += __shfl_xor(s2, off);
            s3 += __shfl_xor(s3, off);
        }
        if (lane == 0) {
            const float t = rsig * (s1 - mu * s2) + s3 + b3[0];
            out[131072 + bt] = fmaxf(t, 0.f) + log1pf(expf(-fabsf(t)));
        }
    }
}

extern "C" void kernel_launch(void* const* d_in, const int* in_sizes, int n_in,
                              void* d_out, int out_size, void* d_ws, size_t ws_size,
                              hipStream_t stream) {
    const float* text   = (const float*)d_in[0];
    const float* audio  = (const float*)d_in[1];
    const float* a_w1   = (const float*)d_in[2];
    const float* a_b1   = (const float*)d_in[3];
    const float* a_w2   = (const float*)d_in[4];
    const float* a_b2   = (const float*)d_in[5];
    const float* d_w1   = (const float*)d_in[6];
    const float* d_b1   = (const float*)d_in[7];
    const float* gn1_g  = (const float*)d_in[8];
    const float* gn1_b  = (const float*)d_in[9];
    const float* d_w2   = (const float*)d_in[10];
    const float* d_b2   = (const float*)d_in[11];
    const float* gn2_g  = (const float*)d_in[12];
    const float* gn2_b  = (const float*)d_in[13];
    const float* d_w3   = (const float*)d_in[14];
    const float* d_b3   = (const float*)d_in[15];

    char* ws = (char*)d_ws;
    float* outf = (float*)d_out;

    bf16_t* text_bf  = (bf16_t*)(ws + OFF_TEXTBF);
    bf16_t* audio_bf = (bf16_t*)(ws + OFF_AUDIOBF);
    bf16_t* w1topT   = (bf16_t*)(ws + OFF_W1TOP);
    bf16_t* w1botT   = (bf16_t*)(ws + OFF_W1BOT);
    bf16_t* wc1      = (bf16_t*)(ws + OFF_WC1);
    bf16_t* wc2      = (bf16_t*)(ws + OFF_WC2);
    f16_t*  tp       = (f16_t*) (ws + OFF_TP);
    f16_t*  w2f      = (f16_t*) (ws + OFF_W2F);
    f16_t*  apT4     = (f16_t*) (ws + OFF_APT);
    bf16_t* xp0      = (bf16_t*)(ws + OFF_XP0);
    bf16_t* xp1      = (bf16_t*)(ws + OFF_XP1);
    bf16_t* y2       = (bf16_t*)(ws + OFF_Y2);
    float*  bstat1   = (float*) (ws + OFF_BST1);
    float*  bstat2   = (float*) (ws + OFF_BST2);
    float*  lp       = (float*) (ws + OFF_LP);

    // 1: prep (cvt activations, w1 transpose, conv weights, pads, w2f)
    prep_k<<<dim3(5377), 256, 0, stream>>>(text, audio, a_w1, d_w1, d_w2, a_w2,
                                           text_bf, xp0, audio_bf, w1topT, w1botT,
                                           wc1, wc2, xp1, w2f);
    // 2: conv1 (blocks 0..511, XCD-swizzled, atomic-free) ∥ tp/ap GEMM
    p2_k<<<dim3(1152), 512, 0, stream>>>(wc1, xp0, d_b1, xp1, bstat1,
                                         text_bf, w1topT, a_b1, tp,
                                         audio_bf, w1botT, apT4);
    // 3: logits partials (0..255) ∥ GN1 reduce+apply (256..383)
    p3_k<<<dim3(384), 512, 0, stream>>>(tp, apT4, w2f, lp,
                                        xp1, bstat1, gn1_g, gn1_b);
    // 4: conv2 -> y2 (pre-GN2, atomic-free)
    conv2_k<<<dim3(512), 512, 0, stream>>>(wc2, xp1, d_b2, y2, bstat2);
    // 5: combine+softmax -> alignment; conv3+GN2(reduced)+softplus -> durations
    combine_k<<<dim3(288), 512, 0, stream>>>(lp, a_b2, y2, bstat2,
                                             gn2_g, gn2_b, d_w3, d_b3, outf);
}